// Round 1
// baseline (1039.034 us; speedup 1.0000x reference)
//
#include <hip/hip_runtime.h>
#include <math.h>

#define NEDGE 600000
#define NUSER 50000
#define NITEM 50000
#define DIMT  128
#define NIN   25000

// ---------------------------------------------------------------------------
// Timestep embedding: out[n][c] = c<64 ? cos(t*freq[c]) : sin(t*freq[c&63])
// freq computed with numpy-matching fp32 rounding sequence; trig in f64 on the
// fp32 argument (arg up to ~999 rad: must not re-round the argument).
// ---------------------------------------------------------------------------
__global__ __launch_bounds__(256) void emb_kernel(const int* __restrict__ t,
                                                  float* __restrict__ out, int N) {
    int idx = blockIdx.x * 256 + threadIdx.x;
    if (idx >= N * 128) return;
    int n = idx >> 7, c = idx & 127;
    int j = c & 63;
    const float Lf = 9.210340371976184f;      // fp32(log(10000))
    float p  = -Lf * (float)j;                // fp32 multiply (numpy order)
    float ae = p * 0.015625f;                 // /64 exact
    float freq = (float)exp((double)ae);      // ~correctly-rounded fp32 exp
    float arg  = (float)t[n] * freq;          // fp32 rounding matches numpy
    double a = (double)arg;
    out[idx] = (c < 64) ? (float)cos(a) : (float)sin(a);
}

// ---------------------------------------------------------------------------
// Generic fused dense:  Y = act( A@W1 [+ B@W2] + bias [+ res] )
// Row-major A[M][K], W[K][NOUT]. K multiple of 32. NOUT in {32,64,128,256}.
// BM=64 rows/block, 256 threads, per-thread microtile RM x 8.
// ---------------------------------------------------------------------------
#define ACT_NONE 0
#define ACT_RELU 1
#define ACT_SILU 2

template<int NOUT, int ACT, bool DUAL, bool HASRES>
__global__ __launch_bounds__(256)
void dense_kernel(const float* __restrict__ A, const float* __restrict__ W1, int K1,
                  const float* __restrict__ B, const float* __restrict__ W2, int K2,
                  const float* __restrict__ bias, const float* __restrict__ res,
                  float* __restrict__ Y, int M) {
    constexpr int BM = 64, BK = 32, VN = 8;
    constexpr int TX = NOUT / VN;     // threads along N
    constexpr int TY = 256 / TX;
    constexpr int RM = BM / TY;       // rows per thread

    __shared__ float sA[BM][BK + 4];  // stride 36 floats: 16B-aligned f4 writes, 2-way-max read conflicts
    __shared__ float sW[BK][NOUT];

    const int tid = threadIdx.x;
    const int tx  = tid % TX;
    const int ty  = tid / TX;
    const int m0  = blockIdx.x * BM;
    const int rowb = ty * RM;

    float acc[RM][VN];
#pragma unroll
    for (int i = 0; i < RM; ++i)
#pragma unroll
        for (int j = 0; j < VN; ++j) acc[i][j] = 0.f;

    const int nPhases = DUAL ? 2 : 1;
    for (int ph = 0; ph < nPhases; ++ph) {
        const float* __restrict__ X = (ph == 0) ? A : B;
        const float* __restrict__ W = (ph == 0) ? W1 : W2;
        const int K = (ph == 0) ? K1 : K2;
        for (int k0 = 0; k0 < K; k0 += BK) {
            // stage A tile 64x32
#pragma unroll
            for (int r = 0; r < 2; ++r) {
                int idx = tid + r * 256;
                int row = idx >> 3;
                int kq  = idx & 7;
                int m = m0 + row;
                float4 v = make_float4(0.f, 0.f, 0.f, 0.f);
                if (m < M) v = *reinterpret_cast<const float4*>(X + (size_t)m * K + k0 + kq * 4);
                *reinterpret_cast<float4*>(&sA[row][kq * 4]) = v;
            }
            // stage W tile 32xNOUT
            constexpr int WITER = (BK * NOUT) / (4 * 256);
#pragma unroll
            for (int r = 0; r < WITER; ++r) {
                int idx = tid + r * 256;
                int row = idx / (NOUT / 4);
                int nq  = idx % (NOUT / 4);
                float4 v = *reinterpret_cast<const float4*>(W + (size_t)(k0 + row) * NOUT + nq * 4);
                *reinterpret_cast<float4*>(&sW[row][nq * 4]) = v;
            }
            __syncthreads();
#pragma unroll
            for (int k = 0; k < BK; ++k) {
                float w[VN];
                *reinterpret_cast<float4*>(&w[0]) = *reinterpret_cast<const float4*>(&sW[k][tx * VN]);
                *reinterpret_cast<float4*>(&w[4]) = *reinterpret_cast<const float4*>(&sW[k][tx * VN + 4]);
#pragma unroll
                for (int i = 0; i < RM; ++i) {
                    float a = sA[rowb + i][k];
#pragma unroll
                    for (int j = 0; j < VN; ++j) acc[i][j] = fmaf(a, w[j], acc[i][j]);
                }
            }
            __syncthreads();
        }
    }

    // epilogue
    float4 bb0 = *reinterpret_cast<const float4*>(bias + tx * VN);
    float4 bb1 = *reinterpret_cast<const float4*>(bias + tx * VN + 4);
#pragma unroll
    for (int i = 0; i < RM; ++i) {
        int m = m0 + rowb + i;
        if (m >= M) continue;
        float v[VN];
        v[0] = acc[i][0] + bb0.x; v[1] = acc[i][1] + bb0.y;
        v[2] = acc[i][2] + bb0.z; v[3] = acc[i][3] + bb0.w;
        v[4] = acc[i][4] + bb1.x; v[5] = acc[i][5] + bb1.y;
        v[6] = acc[i][6] + bb1.z; v[7] = acc[i][7] + bb1.w;
        if (HASRES) {
            float4 r0 = *reinterpret_cast<const float4*>(res + (size_t)m * NOUT + tx * VN);
            float4 r1 = *reinterpret_cast<const float4*>(res + (size_t)m * NOUT + tx * VN + 4);
            v[0] += r0.x; v[1] += r0.y; v[2] += r0.z; v[3] += r0.w;
            v[4] += r1.x; v[5] += r1.y; v[6] += r1.z; v[7] += r1.w;
        }
#pragma unroll
        for (int j = 0; j < VN; ++j) {
            float x = v[j];
            if (ACT == ACT_RELU) x = fmaxf(x, 0.f);
            else if (ACT == ACT_SILU) { float s = 1.f / (1.f + expf(-x)); x = x * s; }
            v[j] = x;
        }
        *reinterpret_cast<float4*>(Y + (size_t)m * NOUT + tx * VN)     = make_float4(v[0], v[1], v[2], v[3]);
        *reinterpret_cast<float4*>(Y + (size_t)m * NOUT + tx * VN + 4) = make_float4(v[4], v[5], v[6], v[7]);
    }
}

// ---------------------------------------------------------------------------
// CSR build: histogram -> 3-kernel exclusive scan -> atomic bucket fill
// ---------------------------------------------------------------------------
__global__ __launch_bounds__(256) void hist_kernel(const int* __restrict__ dst,
                                                   int* __restrict__ cnt, int E) {
    int e = blockIdx.x * 256 + threadIdx.x;
    if (e < E) atomicAdd(&cnt[dst[e]], 1);
}

#define SCAN_CHUNK 2048
__global__ __launch_bounds__(256) void scan1_kernel(const int* __restrict__ cnt,
                                                    int* __restrict__ bsum, int N) {
    __shared__ int sdata[256];
    int base = blockIdx.x * SCAN_CHUNK + threadIdx.x * 8;
    int s = 0;
#pragma unroll
    for (int j = 0; j < 8; ++j) { int i = base + j; if (i < N) s += cnt[i]; }
    sdata[threadIdx.x] = s;
    __syncthreads();
    for (int st = 128; st > 0; st >>= 1) {
        if ((int)threadIdx.x < st) sdata[threadIdx.x] += sdata[threadIdx.x + st];
        __syncthreads();
    }
    if (threadIdx.x == 0) bsum[blockIdx.x] = sdata[0];
}

__global__ void scan2_kernel(int* __restrict__ bsum, int G) {
    if (threadIdx.x == 0 && blockIdx.x == 0) {
        int run = 0;
        for (int b = 0; b < G; ++b) { int v = bsum[b]; bsum[b] = run; run += v; }
    }
}

__global__ __launch_bounds__(256) void scan3_kernel(const int* __restrict__ cnt,
                                                    const int* __restrict__ bsum,
                                                    int* __restrict__ offs,
                                                    int* __restrict__ wp, int N) {
    __shared__ int sth[256];
    int t = threadIdx.x;
    int base = blockIdx.x * SCAN_CHUNK + t * 8;
    int loc[8];
    int s = 0;
#pragma unroll
    for (int j = 0; j < 8; ++j) {
        int i = base + j;
        int v = (i < N) ? cnt[i] : 0;
        loc[j] = s; s += v;
    }
    sth[t] = s;
    __syncthreads();
    for (int st = 1; st < 256; st <<= 1) {
        int v = (t >= st) ? sth[t - st] : 0;
        __syncthreads();
        sth[t] += v;
        __syncthreads();
    }
    int exc = (t == 0) ? 0 : sth[t - 1];
    int boff = bsum[blockIdx.x];
#pragma unroll
    for (int j = 0; j < 8; ++j) {
        int i = base + j;
        if (i < N) { int o = boff + exc + loc[j]; offs[i] = o; wp[i] = o; }
    }
    if (blockIdx.x == gridDim.x - 1 && t == 255) offs[N] = boff + sth[255];
}

__global__ __launch_bounds__(256) void fill_kernel(const int* __restrict__ src,
                                                   const int* __restrict__ dst,
                                                   int* __restrict__ wp,
                                                   int* __restrict__ bkt, int E) {
    int e = blockIdx.x * 256 + threadIdx.x;
    if (e < E) {
        int d = dst[e];
        int p = atomicAdd(&wp[d], 1);
        bkt[p] = src[e];
    }
}

// ---------------------------------------------------------------------------
// Segment mean via CSR: one wave per dst row; lane reads float2 (cols 2L,2L+1)
// ---------------------------------------------------------------------------
__global__ __launch_bounds__(256) void gather_mean_kernel(const float* __restrict__ hsrc,
                                                          const int* __restrict__ offs,
                                                          const int* __restrict__ bkt,
                                                          float* __restrict__ mean, int Ndst) {
    int w = (blockIdx.x * 256 + threadIdx.x) >> 6;
    int lane = threadIdx.x & 63;
    if (w >= Ndst) return;
    int beg = offs[w], end = offs[w + 1];
    const float2* __restrict__ base = reinterpret_cast<const float2*>(hsrc);
    float ax = 0.f, ay = 0.f;
    for (int e = beg; e < end; ++e) {
        int s = bkt[e];
        float2 v = base[(size_t)s * 64 + lane];
        ax += v.x; ay += v.y;
    }
    float d = (float)max(end - beg, 1);
    reinterpret_cast<float2*>(mean)[(size_t)w * 64 + lane] = make_float2(ax / d, ay / d);
}

// ---------------------------------------------------------------------------
extern "C" void kernel_launch(void* const* d_in, const int* in_sizes, int n_in,
                              void* d_out, int out_size, void* d_ws, size_t ws_size,
                              hipStream_t stream) {
    const float* x_user  = (const float*)d_in[0];
    const float* x_item  = (const float*)d_in[1];
    const int*   t_user  = (const int*)d_in[2];
    const int*   t_item  = (const int*)d_in[3];
    const int*   eui_src = (const int*)d_in[4];
    const int*   eui_dst = (const int*)d_in[5];
    const int*   eiu_src = (const int*)d_in[6];
    const int*   eiu_dst = (const int*)d_in[7];
    const float* te_W1 = (const float*)d_in[8];  const float* te_b1 = (const float*)d_in[9];
    const float* te_W2 = (const float*)d_in[10]; const float* te_b2 = (const float*)d_in[11];
    const float* proj_Wu = (const float*)d_in[12]; const float* proj_bu = (const float*)d_in[13];
    const float* proj_Wi = (const float*)d_in[14]; const float* proj_bi = (const float*)d_in[15];
    const float* sage_Wnbr  = (const float*)d_in[16];
    const float* sage_Wroot = (const float*)d_in[17];
    const float* sage_b     = (const float*)d_in[18];
    const float* mu_W1 = (const float*)d_in[19]; const float* mu_b1 = (const float*)d_in[20];
    const float* mu_W2 = (const float*)d_in[21]; const float* mu_b2 = (const float*)d_in[22];
    const float* mu_W3 = (const float*)d_in[23]; const float* mu_b3 = (const float*)d_in[24];
    const float* mi_W1 = (const float*)d_in[25]; const float* mi_b1 = (const float*)d_in[26];
    const float* mi_W2 = (const float*)d_in[27]; const float* mi_b2 = (const float*)d_in[28];
    const float* mi_W3 = (const float*)d_in[29]; const float* mi_b3 = (const float*)d_in[30];

    float* out_u = (float*)d_out;                  // [25000][64]
    float* out_i = out_u + (size_t)NIN * 64;       // [25000][32]

    // workspace layout: 4 big activation buffers + CSR int pool (~108 MB)
    const size_t NBIG = (size_t)NUSER * DIMT;      // 6.4M floats
    float* ws = (float*)d_ws;
    float* B0 = ws;
    float* B1 = ws + NBIG;
    float* B2 = ws + 2 * NBIG;
    float* B3 = ws + 3 * NBIG;
    int* ip = (int*)(ws + 4 * NBIG);
    int* off_ui = ip;              ip += NITEM + 1;
    int* wp_ui  = ip;              ip += NITEM;
    int* cnt_ui = ip;              ip += NITEM;
    int* bkt_ui = ip;              ip += NEDGE;
    int* bsum_ui = ip;             ip += 64;
    int* off_iu = ip;              ip += NUSER + 1;
    int* wp_iu  = ip;              ip += NUSER;
    int* cnt_iu = ip;              ip += NUSER;
    int* bkt_iu = ip;              ip += NEDGE;
    int* bsum_iu = ip;             ip += 64;

    const int gDense50k = (NUSER + 63) / 64;       // 782
    const int gDense25k = (NIN + 63) / 64;         // 391
    const int gEdges = (NEDGE + 255) / 256;        // 2344
    const int gScan  = (NUSER + SCAN_CHUNK - 1) / SCAN_CHUNK;  // 25
    const int gEmb   = (NUSER * 128 + 255) / 256;  // 25000
    const int gGather = NUSER * 64 / 256;          // 12500

    // ---- stage A: h = x@proj_W + proj_b + time_mlp(t) ----
    emb_kernel<<<gEmb, 256, 0, stream>>>(t_user, B2, NUSER);
    dense_kernel<128, ACT_SILU, false, false><<<gDense50k, 256, 0, stream>>>(
        B2, te_W1, 128, nullptr, nullptr, 0, te_b1, nullptr, B3, NUSER);
    dense_kernel<128, ACT_NONE, false, false><<<gDense50k, 256, 0, stream>>>(
        B3, te_W2, 128, nullptr, nullptr, 0, te_b2, nullptr, B2, NUSER);
    dense_kernel<128, ACT_NONE, false, true><<<gDense50k, 256, 0, stream>>>(
        x_user, proj_Wu, 64, nullptr, nullptr, 0, proj_bu, B2, B0, NUSER);

    emb_kernel<<<gEmb, 256, 0, stream>>>(t_item, B2, NITEM);
    dense_kernel<128, ACT_SILU, false, false><<<gDense50k, 256, 0, stream>>>(
        B2, te_W1, 128, nullptr, nullptr, 0, te_b1, nullptr, B3, NITEM);
    dense_kernel<128, ACT_NONE, false, false><<<gDense50k, 256, 0, stream>>>(
        B3, te_W2, 128, nullptr, nullptr, 0, te_b2, nullptr, B2, NITEM);
    dense_kernel<128, ACT_NONE, false, true><<<gDense50k, 256, 0, stream>>>(
        x_item, proj_Wi, 32, nullptr, nullptr, 0, proj_bi, B2, B1, NITEM);

    // ---- CSR build (edges constant across layers: build once, use twice) ----
    hipMemsetAsync(cnt_ui, 0, NITEM * sizeof(int), stream);
    hist_kernel<<<gEdges, 256, 0, stream>>>(eui_dst, cnt_ui, NEDGE);
    scan1_kernel<<<gScan, 256, 0, stream>>>(cnt_ui, bsum_ui, NITEM);
    scan2_kernel<<<1, 64, 0, stream>>>(bsum_ui, gScan);
    scan3_kernel<<<gScan, 256, 0, stream>>>(cnt_ui, bsum_ui, off_ui, wp_ui, NITEM);
    fill_kernel<<<gEdges, 256, 0, stream>>>(eui_src, eui_dst, wp_ui, bkt_ui, NEDGE);

    hipMemsetAsync(cnt_iu, 0, NUSER * sizeof(int), stream);
    hist_kernel<<<gEdges, 256, 0, stream>>>(eiu_dst, cnt_iu, NEDGE);
    scan1_kernel<<<gScan, 256, 0, stream>>>(cnt_iu, bsum_iu, NUSER);
    scan2_kernel<<<1, 64, 0, stream>>>(bsum_iu, gScan);
    scan3_kernel<<<gScan, 256, 0, stream>>>(cnt_iu, bsum_iu, off_iu, wp_iu, NUSER);
    fill_kernel<<<gEdges, 256, 0, stream>>>(eiu_src, eiu_dst, wp_iu, bkt_iu, NEDGE);

    // ---- SAGE layers ----
    float* hu = B0; float* hi = B1; float* ta = B2; float* tb = B3;
    for (int l = 0; l < 2; ++l) {
        const float* Wn0 = sage_Wnbr  + (size_t)(l * 2 + 0) * DIMT * DIMT;
        const float* Wr0 = sage_Wroot + (size_t)(l * 2 + 0) * DIMT * DIMT;
        const float* sb0 = sage_b     + (size_t)(l * 2 + 0) * DIMT;
        const float* Wn1 = sage_Wnbr  + (size_t)(l * 2 + 1) * DIMT * DIMT;
        const float* Wr1 = sage_Wroot + (size_t)(l * 2 + 1) * DIMT * DIMT;
        const float* sb1 = sage_b     + (size_t)(l * 2 + 1) * DIMT;

        // new_i = relu(mean(h_u over e_ui)@Wn0 + h_i@Wr0 + b0) -> tb
        gather_mean_kernel<<<gGather, 256, 0, stream>>>(hu, off_ui, bkt_ui, ta, NITEM);
        dense_kernel<128, ACT_RELU, true, false><<<gDense50k, 256, 0, stream>>>(
            ta, Wn0, DIMT, hi, Wr0, DIMT, sb0, nullptr, tb, NITEM);
        // new_u = relu(mean(h_i over e_iu)@Wn1 + h_u@Wr1 + b1) -> old hi buffer
        gather_mean_kernel<<<gGather, 256, 0, stream>>>(hi, off_iu, bkt_iu, ta, NUSER);
        dense_kernel<128, ACT_RELU, true, false><<<gDense50k, 256, 0, stream>>>(
            ta, Wn1, DIMT, hu, Wr1, DIMT, sb1, nullptr, hi, NUSER);

        float* ohu = hu; float* ohi = hi; float* ota = ta; float* otb = tb;
        hu = ohi; hi = otb; ta = ohu; tb = ota;
    }

    // ---- MLP heads (first 25000 rows are a contiguous prefix) ----
    dense_kernel<256, ACT_RELU, false, false><<<gDense25k, 256, 0, stream>>>(
        hu, mu_W1, 128, nullptr, nullptr, 0, mu_b1, nullptr, ta, NIN);
    dense_kernel<256, ACT_RELU, false, false><<<gDense25k, 256, 0, stream>>>(
        ta, mu_W2, 256, nullptr, nullptr, 0, mu_b2, nullptr, tb, NIN);
    dense_kernel<64, ACT_NONE, false, false><<<gDense25k, 256, 0, stream>>>(
        tb, mu_W3, 256, nullptr, nullptr, 0, mu_b3, nullptr, out_u, NIN);

    dense_kernel<256, ACT_RELU, false, false><<<gDense25k, 256, 0, stream>>>(
        hi, mi_W1, 128, nullptr, nullptr, 0, mi_b1, nullptr, ta, NIN);
    dense_kernel<256, ACT_RELU, false, false><<<gDense25k, 256, 0, stream>>>(
        ta, mi_W2, 256, nullptr, nullptr, 0, mi_b2, nullptr, tb, NIN);
    dense_kernel<32, ACT_NONE, false, false><<<gDense25k, 256, 0, stream>>>(
        tb, mi_W3, 256, nullptr, nullptr, 0, mi_b3, nullptr, out_i, NIN);

    (void)in_sizes; (void)n_in; (void)out_size; (void)ws_size;
}

// Round 2
// 950.089 us; speedup vs baseline: 1.0936x; 1.0936x over previous
//
#include <hip/hip_runtime.h>
#include <math.h>

#define NEDGE 600000
#define NUSER 50000
#define NITEM 50000
#define DIMT  128
#define NIN   25000
#define NTVAL 1000

// ---------------------------------------------------------------------------
// Timestep-embedding LUT: t in [0,1000) -> emb[t][c], bitwise-identical to
// per-row computation (t only enters as (float)t * freq).
// ---------------------------------------------------------------------------
__global__ __launch_bounds__(256) void emb_lut_kernel(float* __restrict__ out) {
    int idx = blockIdx.x * 256 + threadIdx.x;
    if (idx >= NTVAL * 128) return;
    int n = idx >> 7, c = idx & 127;
    int j = c & 63;
    const float Lf = 9.210340371976184f;      // fp32(log(10000))
    float p  = -Lf * (float)j;                // numpy op order
    float ae = p * 0.015625f;                 // /64 exact
    float freq = (float)exp((double)ae);
    float arg  = (float)n * freq;             // fp32 rounding matches numpy
    double a = (double)arg;
    out[idx] = (c < 64) ? (float)cos(a) : (float)sin(a);
}

// ---------------------------------------------------------------------------
// Paired fused dense:  Y = act( A@W1 [+ B@W2] + bias [+ res] )
// Two independent problems per launch (blockIdx < q0.nblk -> q0 else q1).
// BM=64 rows/block, 256 threads, microtile RM x 8, reg-prefetch staging.
// RESMODE: 0 none, 1 res[m], 2 res[tidx[m]] (timestep-LUT gather).
// ---------------------------------------------------------------------------
#define ACT_NONE 0
#define ACT_RELU 1
#define ACT_SILU 2

struct DenseProb {
    const float* A; const float* W1; int K1;
    const float* B; const float* W2; int K2;
    const float* bias; const float* res; const int* tidx;
    float* Y; int M; int nblk;
};

template<int NOUT, int ACT, bool DUAL, int RESMODE>
__global__ __launch_bounds__(256)
void dense2_kernel(DenseProb q0, DenseProb q1) {
    constexpr int BM = 64, BK = 32, VN = 8;
    constexpr int TX = NOUT / VN;
    constexpr int TY = 256 / TX;
    constexpr int RM = BM / TY;
    constexpr int WITER = (BK * NOUT) / (4 * 256);

    __shared__ float sA[BM][BK + 4];
    __shared__ float sW[BK][NOUT];

    const bool first = (blockIdx.x < (unsigned)q0.nblk);
    const DenseProb& q = first ? q0 : q1;
    const int bid = first ? blockIdx.x : (blockIdx.x - q0.nblk);

    const int tid = threadIdx.x;
    const int tx  = tid % TX;
    const int ty  = tid / TX;
    const int m0  = bid * BM;
    const int rowb = ty * RM;

    float acc[RM][VN];
#pragma unroll
    for (int i = 0; i < RM; ++i)
#pragma unroll
        for (int j = 0; j < VN; ++j) acc[i][j] = 0.f;

    const int nkt1 = q.K1 / BK;
    const int nkt  = nkt1 + (DUAL ? q.K2 / BK : 0);

    float4 ar[2];
    float4 wr[WITER];

    auto issue = [&](int kt) {
        const float* X; const float* W; int K; int kk;
        if (!DUAL || kt < nkt1) { X = q.A; W = q.W1; K = q.K1; kk = kt * BK; }
        else                    { X = q.B; W = q.W2; K = q.K2; kk = (kt - nkt1) * BK; }
#pragma unroll
        for (int r = 0; r < 2; ++r) {
            int idx = tid + r * 256;
            int row = idx >> 3, kq = idx & 7;
            int m = m0 + row;
            ar[r] = make_float4(0.f, 0.f, 0.f, 0.f);
            if (m < q.M) ar[r] = *reinterpret_cast<const float4*>(X + (size_t)m * K + kk + kq * 4);
        }
#pragma unroll
        for (int r = 0; r < WITER; ++r) {
            int idx = tid + r * 256;
            int row = idx / (NOUT / 4), nq = idx % (NOUT / 4);
            wr[r] = *reinterpret_cast<const float4*>(W + (size_t)(kk + row) * NOUT + nq * 4);
        }
    };
    auto commit = [&]() {
#pragma unroll
        for (int r = 0; r < 2; ++r) {
            int idx = tid + r * 256;
            int row = idx >> 3, kq = idx & 7;
            *reinterpret_cast<float4*>(&sA[row][kq * 4]) = ar[r];
        }
#pragma unroll
        for (int r = 0; r < WITER; ++r) {
            int idx = tid + r * 256;
            int row = idx / (NOUT / 4), nq = idx % (NOUT / 4);
            *reinterpret_cast<float4*>(&sW[row][nq * 4]) = wr[r];
        }
    };

    issue(0);
    for (int kt = 0; kt < nkt; ++kt) {
        commit();
        __syncthreads();
        if (kt + 1 < nkt) issue(kt + 1);   // overlap next-tile global latency with compute
#pragma unroll
        for (int k = 0; k < BK; ++k) {
            float w[VN];
            *reinterpret_cast<float4*>(&w[0]) = *reinterpret_cast<const float4*>(&sW[k][tx * VN]);
            *reinterpret_cast<float4*>(&w[4]) = *reinterpret_cast<const float4*>(&sW[k][tx * VN + 4]);
#pragma unroll
            for (int i = 0; i < RM; ++i) {
                float a = sA[rowb + i][k];
#pragma unroll
                for (int j = 0; j < VN; ++j) acc[i][j] = fmaf(a, w[j], acc[i][j]);
            }
        }
        __syncthreads();
    }

    // epilogue
    float bb[VN];
    *reinterpret_cast<float4*>(&bb[0]) = *reinterpret_cast<const float4*>(q.bias + tx * VN);
    *reinterpret_cast<float4*>(&bb[4]) = *reinterpret_cast<const float4*>(q.bias + tx * VN + 4);
#pragma unroll
    for (int i = 0; i < RM; ++i) {
        int m = m0 + rowb + i;
        if (m >= q.M) continue;
        float v[VN];
#pragma unroll
        for (int j = 0; j < VN; ++j) v[j] = acc[i][j] + bb[j];
        if (RESMODE != 0) {
            const float* rp;
            if (RESMODE == 2) { int tv = q.tidx[m]; rp = q.res + (size_t)tv * NOUT; }
            else              { rp = q.res + (size_t)m * NOUT; }
            float4 r0 = *reinterpret_cast<const float4*>(rp + tx * VN);
            float4 r1 = *reinterpret_cast<const float4*>(rp + tx * VN + 4);
            v[0] += r0.x; v[1] += r0.y; v[2] += r0.z; v[3] += r0.w;
            v[4] += r1.x; v[5] += r1.y; v[6] += r1.z; v[7] += r1.w;
        }
#pragma unroll
        for (int j = 0; j < VN; ++j) {
            float x = v[j];
            if (ACT == ACT_RELU) x = fmaxf(x, 0.f);
            else if (ACT == ACT_SILU) { float s = 1.f / (1.f + expf(-x)); x = x * s; }
            v[j] = x;
        }
        *reinterpret_cast<float4*>(q.Y + (size_t)m * NOUT + tx * VN)     = make_float4(v[0], v[1], v[2], v[3]);
        *reinterpret_cast<float4*>(q.Y + (size_t)m * NOUT + tx * VN + 4) = make_float4(v[4], v[5], v[6], v[7]);
    }
}

// ---------------------------------------------------------------------------
// CSR build: histogram -> 3-kernel exclusive scan -> atomic bucket fill
// ---------------------------------------------------------------------------
__global__ __launch_bounds__(256) void hist_kernel(const int* __restrict__ dst,
                                                   int* __restrict__ cnt, int E) {
    int e = blockIdx.x * 256 + threadIdx.x;
    if (e < E) atomicAdd(&cnt[dst[e]], 1);
}

#define SCAN_CHUNK 2048
__global__ __launch_bounds__(256) void scan1_kernel(const int* __restrict__ cnt,
                                                    int* __restrict__ bsum, int N) {
    __shared__ int sdata[256];
    int base = blockIdx.x * SCAN_CHUNK + threadIdx.x * 8;
    int s = 0;
#pragma unroll
    for (int j = 0; j < 8; ++j) { int i = base + j; if (i < N) s += cnt[i]; }
    sdata[threadIdx.x] = s;
    __syncthreads();
    for (int st = 128; st > 0; st >>= 1) {
        if ((int)threadIdx.x < st) sdata[threadIdx.x] += sdata[threadIdx.x + st];
        __syncthreads();
    }
    if (threadIdx.x == 0) bsum[blockIdx.x] = sdata[0];
}

__global__ void scan2_kernel(int* __restrict__ bsum, int G) {
    if (threadIdx.x == 0 && blockIdx.x == 0) {
        int run = 0;
        for (int b = 0; b < G; ++b) { int v = bsum[b]; bsum[b] = run; run += v; }
    }
}

__global__ __launch_bounds__(256) void scan3_kernel(const int* __restrict__ cnt,
                                                    const int* __restrict__ bsum,
                                                    int* __restrict__ offs,
                                                    int* __restrict__ wp, int N) {
    __shared__ int sth[256];
    int t = threadIdx.x;
    int base = blockIdx.x * SCAN_CHUNK + t * 8;
    int loc[8];
    int s = 0;
#pragma unroll
    for (int j = 0; j < 8; ++j) {
        int i = base + j;
        int v = (i < N) ? cnt[i] : 0;
        loc[j] = s; s += v;
    }
    sth[t] = s;
    __syncthreads();
    for (int st = 1; st < 256; st <<= 1) {
        int v = (t >= st) ? sth[t - st] : 0;
        __syncthreads();
        sth[t] += v;
        __syncthreads();
    }
    int exc = (t == 0) ? 0 : sth[t - 1];
    int boff = bsum[blockIdx.x];
#pragma unroll
    for (int j = 0; j < 8; ++j) {
        int i = base + j;
        if (i < N) { int o = boff + exc + loc[j]; offs[i] = o; wp[i] = o; }
    }
    if (blockIdx.x == gridDim.x - 1 && t == 255) offs[N] = boff + sth[255];
}

__global__ __launch_bounds__(256) void fill_kernel(const int* __restrict__ src,
                                                   const int* __restrict__ dst,
                                                   int* __restrict__ wp,
                                                   int* __restrict__ bkt, int E) {
    int e = blockIdx.x * 256 + threadIdx.x;
    if (e < E) {
        int d = dst[e];
        int p = atomicAdd(&wp[d], 1);
        bkt[p] = src[e];
    }
}

// ---------------------------------------------------------------------------
// Paired segment-mean via CSR: one wave per dst row; lanes 0-31 edge e,
// lanes 32-63 edge e+1, float4 per lane; shfl_xor(32) combines halves.
// ---------------------------------------------------------------------------
struct GatherProb { const float* h; const int* offs; const int* bkt; float* out; int N; };

__global__ __launch_bounds__(256)
void gather2_kernel(GatherProb g0, GatherProb g1) {
    int gw = (blockIdx.x * 256 + threadIdx.x) >> 6;
    int lane = threadIdx.x & 63;
    const bool firstp = (gw < g0.N);
    const GatherProb& g = firstp ? g0 : g1;
    int row = firstp ? gw : gw - g0.N;
    if (row >= g.N) return;
    int beg = g.offs[row], end = g.offs[row + 1];
    int half = lane >> 5, c4 = lane & 31;
    const float4* __restrict__ base = reinterpret_cast<const float4*>(g.h);
    float sx = 0.f, sy = 0.f, sz = 0.f, sw = 0.f;
    for (int e = beg + half; e < end; e += 2) {
        int src = g.bkt[e];
        float4 v = base[(size_t)src * 32 + c4];
        sx += v.x; sy += v.y; sz += v.z; sw += v.w;
    }
    sx += __shfl_xor(sx, 32, 64);
    sy += __shfl_xor(sy, 32, 64);
    sz += __shfl_xor(sz, 32, 64);
    sw += __shfl_xor(sw, 32, 64);
    if (half == 0) {
        float d = (float)max(end - beg, 1);
        reinterpret_cast<float4*>(g.out)[(size_t)row * 32 + c4] =
            make_float4(sx / d, sy / d, sz / d, sw / d);
    }
}

// ---------------------------------------------------------------------------
extern "C" void kernel_launch(void* const* d_in, const int* in_sizes, int n_in,
                              void* d_out, int out_size, void* d_ws, size_t ws_size,
                              hipStream_t stream) {
    const float* x_user  = (const float*)d_in[0];
    const float* x_item  = (const float*)d_in[1];
    const int*   t_user  = (const int*)d_in[2];
    const int*   t_item  = (const int*)d_in[3];
    const int*   eui_src = (const int*)d_in[4];
    const int*   eui_dst = (const int*)d_in[5];
    const int*   eiu_src = (const int*)d_in[6];
    const int*   eiu_dst = (const int*)d_in[7];
    const float* te_W1 = (const float*)d_in[8];  const float* te_b1 = (const float*)d_in[9];
    const float* te_W2 = (const float*)d_in[10]; const float* te_b2 = (const float*)d_in[11];
    const float* proj_Wu = (const float*)d_in[12]; const float* proj_bu = (const float*)d_in[13];
    const float* proj_Wi = (const float*)d_in[14]; const float* proj_bi = (const float*)d_in[15];
    const float* sage_Wnbr  = (const float*)d_in[16];
    const float* sage_Wroot = (const float*)d_in[17];
    const float* sage_b     = (const float*)d_in[18];
    const float* mu_W1 = (const float*)d_in[19]; const float* mu_b1 = (const float*)d_in[20];
    const float* mu_W2 = (const float*)d_in[21]; const float* mu_b2 = (const float*)d_in[22];
    const float* mu_W3 = (const float*)d_in[23]; const float* mu_b3 = (const float*)d_in[24];
    const float* mi_W1 = (const float*)d_in[25]; const float* mi_b1 = (const float*)d_in[26];
    const float* mi_W2 = (const float*)d_in[27]; const float* mi_b2 = (const float*)d_in[28];
    const float* mi_W3 = (const float*)d_in[29]; const float* mi_b3 = (const float*)d_in[30];

    float* out_u = (float*)d_out;                  // [25000][64]
    float* out_i = out_u + (size_t)NIN * 64;       // [25000][32]

    // workspace: 4 big ping-pong buffers + LUT + CSR int pool
    const size_t NBIG = (size_t)NUSER * DIMT;      // 6.4M floats (25.6 MB)
    float* ws = (float*)d_ws;
    float* P0 = ws;
    float* P1 = ws + NBIG;
    float* P2 = ws + 2 * NBIG;
    float* P3 = ws + 3 * NBIG;
    float* Elut = ws + 4 * NBIG;                   // 1000*128
    float* Ttmp = Elut + NTVAL * 128;
    float* Tlut = Ttmp + NTVAL * 128;
    int* ip = (int*)(Tlut + NTVAL * 128);
    int* off_ui = ip;              ip += NITEM + 1;
    int* wp_ui  = ip;              ip += NITEM;
    int* cnt_ui = ip;              ip += NITEM;
    int* bkt_ui = ip;              ip += NEDGE;
    int* bsum_ui = ip;             ip += 64;
    int* off_iu = ip;              ip += NUSER + 1;
    int* wp_iu  = ip;              ip += NUSER;
    int* cnt_iu = ip;              ip += NUSER;
    int* bkt_iu = ip;              ip += NEDGE;
    int* bsum_iu = ip;             ip += 64;

    const int nb50k = (NUSER + 63) / 64;           // 782
    const int nb25k = (NIN + 63) / 64;             // 391
    const int nbLut = (NTVAL + 63) / 64;           // 16
    const int gEdges = (NEDGE + 255) / 256;
    const int gScan  = (NUSER + SCAN_CHUNK - 1) / SCAN_CHUNK;

    DenseProb qn = {};  // null slot

    // ---- timestep-MLP LUT (1000 rows) ----
    emb_lut_kernel<<<(NTVAL * 128 + 255) / 256, 256, 0, stream>>>(Elut);
    {
        DenseProb q = { Elut, te_W1, 128, nullptr, nullptr, 0, te_b1, nullptr, nullptr, Ttmp, NTVAL, nbLut };
        dense2_kernel<128, ACT_SILU, false, 0><<<nbLut, 256, 0, stream>>>(q, qn);
    }
    {
        DenseProb q = { Ttmp, te_W2, 128, nullptr, nullptr, 0, te_b2, nullptr, nullptr, Tlut, NTVAL, nbLut };
        dense2_kernel<128, ACT_NONE, false, 0><<<nbLut, 256, 0, stream>>>(q, qn);
    }

    // ---- proj (merged user+item): h = x@proj_W + b + Tlut[t] ----
    {
        DenseProb qu = { x_user, proj_Wu, 64, nullptr, nullptr, 0, proj_bu, Tlut, t_user, P0, NUSER, nb50k };
        DenseProb qi = { x_item, proj_Wi, 32, nullptr, nullptr, 0, proj_bi, Tlut, t_item, P1, NITEM, nb50k };
        dense2_kernel<128, ACT_NONE, false, 2><<<2 * nb50k, 256, 0, stream>>>(qu, qi);
    }

    // ---- CSR build (edges constant across layers) ----
    hipMemsetAsync(cnt_ui, 0, NITEM * sizeof(int), stream);
    hist_kernel<<<gEdges, 256, 0, stream>>>(eui_dst, cnt_ui, NEDGE);
    scan1_kernel<<<gScan, 256, 0, stream>>>(cnt_ui, bsum_ui, NITEM);
    scan2_kernel<<<1, 64, 0, stream>>>(bsum_ui, gScan);
    scan3_kernel<<<gScan, 256, 0, stream>>>(cnt_ui, bsum_ui, off_ui, wp_ui, NITEM);
    fill_kernel<<<gEdges, 256, 0, stream>>>(eui_src, eui_dst, wp_ui, bkt_ui, NEDGE);

    hipMemsetAsync(cnt_iu, 0, NUSER * sizeof(int), stream);
    hist_kernel<<<gEdges, 256, 0, stream>>>(eiu_dst, cnt_iu, NEDGE);
    scan1_kernel<<<gScan, 256, 0, stream>>>(cnt_iu, bsum_iu, NUSER);
    scan2_kernel<<<1, 64, 0, stream>>>(bsum_iu, gScan);
    scan3_kernel<<<gScan, 256, 0, stream>>>(cnt_iu, bsum_iu, off_iu, wp_iu, NUSER);
    fill_kernel<<<gEdges, 256, 0, stream>>>(eiu_src, eiu_dst, wp_iu, bkt_iu, NEDGE);

    // ---- SAGE layers (gather pair merged, dense pair merged) ----
    float* hu = P0; float* hi = P1; float* fa = P2; float* fb = P3;
    for (int l = 0; l < 2; ++l) {
        const float* Wn0 = sage_Wnbr  + (size_t)(l * 2 + 0) * DIMT * DIMT;
        const float* Wr0 = sage_Wroot + (size_t)(l * 2 + 0) * DIMT * DIMT;
        const float* sb0 = sage_b     + (size_t)(l * 2 + 0) * DIMT;
        const float* Wn1 = sage_Wnbr  + (size_t)(l * 2 + 1) * DIMT * DIMT;
        const float* Wr1 = sage_Wroot + (size_t)(l * 2 + 1) * DIMT * DIMT;
        const float* sb1 = sage_b     + (size_t)(l * 2 + 1) * DIMT;

        // mean_i (over e_ui of h_u) -> fa ; mean_u (over e_iu of h_i) -> fb
        {
            GatherProb gi = { hu, off_ui, bkt_ui, fa, NITEM };
            GatherProb gu = { hi, off_iu, bkt_iu, fb, NUSER };
            gather2_kernel<<<(NITEM + NUSER) * 64 / 256, 256, 0, stream>>>(gi, gu);
        }
        // new_i = relu(mean_i@Wn0 + h_i@Wr0 + b0) -> fa (aliases A: per-block rows disjoint)
        // new_u = relu(mean_u@Wn1 + h_u@Wr1 + b1) -> fb
        {
            DenseProb qi = { fa, Wn0, DIMT, hi, Wr0, DIMT, sb0, nullptr, nullptr, fa, NITEM, nb50k };
            DenseProb qu = { fb, Wn1, DIMT, hu, Wr1, DIMT, sb1, nullptr, nullptr, fb, NUSER, nb50k };
            dense2_kernel<128, ACT_RELU, true, 0><<<2 * nb50k, 256, 0, stream>>>(qi, qu);
        }
        // rotate: new h's are fa(fi)/fb(fu); old hu,hi become free
        float* ohu = hu; float* ohi = hi;
        hi = fa; hu = fb; fa = ohu; fb = ohi;
    }

    // ---- MLP heads (first 25000 rows; levels merged across user/item) ----
    float* T0 = fa;  // 25000x256 fits in a big buffer
    float* T1 = fb;
    {
        DenseProb qu = { hu, mu_W1, 128, nullptr, nullptr, 0, mu_b1, nullptr, nullptr, T0, NIN, nb25k };
        DenseProb qi = { hi, mi_W1, 128, nullptr, nullptr, 0, mi_b1, nullptr, nullptr, T1, NIN, nb25k };
        dense2_kernel<256, ACT_RELU, false, 0><<<2 * nb25k, 256, 0, stream>>>(qu, qi);
    }
    {
        DenseProb qu = { T0, mu_W2, 256, nullptr, nullptr, 0, mu_b2, nullptr, nullptr, T0, NIN, nb25k };
        DenseProb qi = { T1, mi_W2, 256, nullptr, nullptr, 0, mi_b2, nullptr, nullptr, T1, NIN, nb25k };
        dense2_kernel<256, ACT_RELU, false, 0><<<2 * nb25k, 256, 0, stream>>>(qu, qi);
    }
    {
        DenseProb q = { T0, mu_W3, 256, nullptr, nullptr, 0, mu_b3, nullptr, nullptr, out_u, NIN, nb25k };
        dense2_kernel<64, ACT_NONE, false, 0><<<nb25k, 256, 0, stream>>>(q, qn);
    }
    {
        DenseProb q = { T1, mi_W3, 256, nullptr, nullptr, 0, mi_b3, nullptr, nullptr, out_i, NIN, nb25k };
        dense2_kernel<32, ACT_NONE, false, 0><<<nb25k, 256, 0, stream>>>(q, qn);
    }

    (void)in_sizes; (void)n_in; (void)out_size; (void)ws_size;
}